// Round 1
// baseline (122.453 us; speedup 1.0000x reference)
//
#include <hip/hip_runtime.h>
#include <hip/hip_bf16.h>

#define NS 8192          // 4*2048 samples
#define D 14
#define CS 16384         // 2^14 codes
#define PARTS 16
#define NSP (NS / PARTS) // 512 samples per part
#define EPS 1e-5f
#define LNEPS (-11.512925464970229f) // ln(1e-5)

// ---------------------------------------------------------------------------
// Kernel A: per-sample projection, quantization, indices, out-projection,
// commit-loss partials, logZ, and the two half-sum tables.
//   At (col-major): At[m*NS + i] = sum_{d<7} s(m,d)*a_d - logZ_i
//   Bt (row-major): Bt[i*128 + l] = sum_{d>=7} s(l,d)*a_d
// with a_d = 200*h_d, sign s from MSB-first bit layout.
// ---------------------------------------------------------------------------
__global__ __launch_bounds__(256) void lfq_kA(
    const float* __restrict__ x, const float* __restrict__ Win,
    const float* __restrict__ bin, const float* __restrict__ Wout,
    const float* __restrict__ bout,
    float* __restrict__ out, float* __restrict__ idxOut,
    float* __restrict__ At, float* __restrict__ Bt,
    float* __restrict__ commitPart)
{
    const int i = blockIdx.x * 256 + threadIdx.x;
    if (i >= NS) return;

    float xv[D];
    #pragma unroll
    for (int k = 0; k < D; k++) xv[k] = x[i * D + k];

    float h[D];
    #pragma unroll
    for (int d = 0; d < D; d++) {
        float s = bin[d];
        #pragma unroll
        for (int k = 0; k < D; k++) s = fmaf(xv[k], Win[d * D + k], s);
        h[d] = s;
    }

    // sign quantization + indices (MSB-first) + commit loss
    float q[D];
    int idx = 0;
    float commit = 0.f;
    #pragma unroll
    for (int d = 0; d < D; d++) {
        const bool pos = h[d] > 0.f;
        q[d] = pos ? 1.f : -1.f;
        idx |= (pos ? 1 : 0) << (13 - d);
        const float e = h[d] - q[d];
        commit = fmaf(e, e, commit);
    }

    // out = q @ W_out.T + b_out   (forward value of straight-through h_st == q)
    #pragma unroll
    for (int e = 0; e < D; e++) {
        float s = bout[e];
        #pragma unroll
        for (int d = 0; d < D; d++) s = fmaf(q[d], Wout[e * D + d], s);
        out[i * D + e] = s;
    }
    idxOut[i] = (float)idx;

    // a_d = 200*h_d ; logZ = sum_d log(2cosh(a_d)) = |a| + log1p(exp(-2|a|))
    float a[D];
    float logZ = 0.f;
    #pragma unroll
    for (int d = 0; d < D; d++) {
        a[d] = 200.0f * h[d];
        const float ab = fabsf(a[d]);
        logZ += ab + log1pf(__expf(-2.f * ab));
    }

    // high-7-bit table (dims 0..6), column-major, logZ folded in
    #pragma unroll
    for (int m = 0; m < 128; m++) {
        float v = -logZ;
        #pragma unroll
        for (int d = 0; d < 7; d++) v += ((m >> (6 - d)) & 1) ? a[d] : -a[d];
        At[m * NS + i] = v;
    }
    // low-7-bit table (dims 7..13), row-major
    #pragma unroll
    for (int l = 0; l < 128; l++) {
        float v = 0.f;
        #pragma unroll
        for (int d = 7; d < D; d++) v += ((l >> (13 - d)) & 1) ? a[d] : -a[d];
        Bt[i * 128 + l] = v;
    }

    // block-reduce commit loss -> one partial per block (no atomics)
    __shared__ float red[256];
    red[threadIdx.x] = commit;
    __syncthreads();
    #pragma unroll
    for (int s = 128; s > 0; s >>= 1) {
        if (threadIdx.x < s) red[threadIdx.x] += red[threadIdx.x + s];
        __syncthreads();
    }
    if (threadIdx.x == 0) commitPart[blockIdx.x] = red[0];
}

// ---------------------------------------------------------------------------
// Kernel B: per (code j, sample-part) accumulation of
//   p_ij = exp(A'[jHi][i] + Bt[i][jLo])          (== softmax prob, analytic)
//   ent partial: sum p * max(t, ln eps)          (matches -p*log(clip(p,eps)))
//   avg_prob partial: sum_i p
// grid = 64 jblocks * 16 parts; thread t owns j = jb*256+t.
// ---------------------------------------------------------------------------
__global__ __launch_bounds__(256) void lfq_kB(
    const float* __restrict__ At, const float* __restrict__ Bt,
    float* __restrict__ avgPart, float* __restrict__ entPart)
{
    const int b = blockIdx.x;          // 0..1023
    const int part = b & (PARTS - 1);  // 0..15
    const int jb = b >> 4;             // 0..63
    const int t = threadIdx.x;
    const int j = jb * 256 + t;
    const int jHi = j >> 7;
    const int jLo = j & 127;

    const float* aCol  = At + jHi * NS + part * NSP;          // wave-uniform
    const float* bBase = Bt + (size_t)(part * NSP) * 128 + jLo; // lane-coalesced

    float ent = 0.f, ap = 0.f;
    #pragma unroll 4
    for (int i = 0; i < NSP; i++) {
        const float av = aCol[i];
        const float bv = bBase[(size_t)i * 128];
        const float tt = av + bv;
        const float p = __expf(tt);
        ent = fmaf(p, fmaxf(tt, LNEPS), ent);
        ap += p;
    }

    avgPart[part * CS + j] = ap;

    __shared__ float red[256];
    red[t] = ent;
    __syncthreads();
    #pragma unroll
    for (int s = 128; s > 0; s >>= 1) {
        if (t < s) red[t] += red[t + s];
        __syncthreads();
    }
    if (t == 0) entPart[b] = red[0];
}

// ---------------------------------------------------------------------------
// Kernel C: final reductions + aux loss scalar.
// ---------------------------------------------------------------------------
__global__ __launch_bounds__(256) void lfq_kC(
    const float* __restrict__ avgPart, const float* __restrict__ entPart,
    const float* __restrict__ commitPart, float* __restrict__ aux)
{
    const int t = threadIdx.x;

    // codebook entropy: q_j = (1/NS) * sum_parts avgPart ; sum q*log(max(q,eps))
    float cb = 0.f;
    for (int j = t; j < CS; j += 256) {
        float s = 0.f;
        #pragma unroll
        for (int p = 0; p < PARTS; p++) s += avgPart[p * CS + j];
        const float q = s * (1.0f / NS);
        cb += q * __logf(fmaxf(q, EPS));
    }
    // per-sample entropy partials (1024 blocks of kernel B)
    float es = 0.f;
    for (int k = t; k < 1024; k += 256) es += entPart[k];
    // commit partials (32 blocks of kernel A)
    float cs = 0.f;
    if (t < 32) cs = commitPart[t];

    __shared__ float r1[256], r2[256], r3[256];
    r1[t] = cb; r2[t] = es; r3[t] = cs;
    __syncthreads();
    #pragma unroll
    for (int s = 128; s > 0; s >>= 1) {
        if (t < s) { r1[t] += r1[t + s]; r2[t] += r2[t + s]; r3[t] += r3[t + s]; }
        __syncthreads();
    }
    if (t == 0) {
        const float codebook_entropy = -r1[0];
        const float per_sample_entropy = -r2[0] / (float)NS;
        const float commit_loss = r3[0] / (float)(NS * D);
        const float entropy_aux = per_sample_entropy - 1.0f * codebook_entropy;
        aux[0] = entropy_aux * 0.1f + commit_loss * 0.25f;
    }
}

extern "C" void kernel_launch(void* const* d_in, const int* in_sizes, int n_in,
                              void* d_out, int out_size, void* d_ws, size_t ws_size,
                              hipStream_t stream) {
    const float* x    = (const float*)d_in[0];
    const float* Win  = (const float*)d_in[1];
    const float* bin  = (const float*)d_in[2];
    const float* Wout = (const float*)d_in[3];
    const float* bout = (const float*)d_in[4];

    float* out    = (float*)d_out;            // [NS][D]
    float* idxOut = out + (size_t)NS * D;     // [NS] indices as float
    float* aux    = idxOut + NS;              // scalar

    float* ws         = (float*)d_ws;
    float* At         = ws;                       // 128*NS floats (4MB)
    float* Bt         = At + (size_t)128 * NS;    // NS*128 floats (4MB)
    float* avgPart    = Bt + (size_t)128 * NS;    // PARTS*CS floats (1MB)
    float* entPart    = avgPart + (size_t)PARTS * CS; // 1024 floats
    float* commitPart = entPart + 1024;           // 32 floats

    lfq_kA<<<NS / 256, 256, 0, stream>>>(x, Win, bin, Wout, bout,
                                         out, idxOut, At, Bt, commitPart);
    lfq_kB<<<64 * PARTS, 256, 0, stream>>>(At, Bt, avgPart, entPart);
    lfq_kC<<<1, 256, 0, stream>>>(avgPart, entPart, commitPart, aux);
}

// Round 2
// 57.892 us; speedup vs baseline: 2.1152x; 2.1152x over previous
//
#include <hip/hip_runtime.h>
#include <hip/hip_bf16.h>

#define NS 8192          // 4*2048 samples
#define D 14
#define CS 16384         // 2^14 codes
#define PARTS 32
#define NSP (NS / PARTS) // 256 samples per part
#define EPS 1e-5f
#define LNEPS (-11.512925464970229f) // ln(1e-5)

// ---------------------------------------------------------------------------
// Kernel A: per-sample projection, quantization, indices, out-projection,
// commit-loss partials, logZ, and the two half-sum tables.
//   At (col-major): At[m*NS + i] = sum_{d<7} s(m,d)*a_d - logZ_i
//   Bt (row-major): Bt[i*128 + l] = sum_{d>=7} s(l,d)*a_d
// 64-thread blocks for CU spread (work per thread is large).
// ---------------------------------------------------------------------------
__global__ __launch_bounds__(64) void lfq_kA(
    const float* __restrict__ x, const float* __restrict__ Win,
    const float* __restrict__ bin, const float* __restrict__ Wout,
    const float* __restrict__ bout,
    float* __restrict__ out, float* __restrict__ idxOut,
    float* __restrict__ At, float* __restrict__ Bt,
    float* __restrict__ commitPart)
{
    const int i = blockIdx.x * 64 + threadIdx.x;

    float xv[D];
    #pragma unroll
    for (int k = 0; k < D; k++) xv[k] = x[i * D + k];

    float h[D];
    #pragma unroll
    for (int d = 0; d < D; d++) {
        float s = bin[d];
        #pragma unroll
        for (int k = 0; k < D; k++) s = fmaf(xv[k], Win[d * D + k], s);
        h[d] = s;
    }

    // sign quantization + indices (MSB-first) + commit loss
    float q[D];
    int idx = 0;
    float commit = 0.f;
    #pragma unroll
    for (int d = 0; d < D; d++) {
        const bool pos = h[d] > 0.f;
        q[d] = pos ? 1.f : -1.f;
        idx |= (pos ? 1 : 0) << (13 - d);
        const float e = h[d] - q[d];
        commit = fmaf(e, e, commit);
    }

    // out = q @ W_out.T + b_out   (forward value of straight-through h_st == q)
    #pragma unroll
    for (int e = 0; e < D; e++) {
        float s = bout[e];
        #pragma unroll
        for (int d = 0; d < D; d++) s = fmaf(q[d], Wout[e * D + d], s);
        out[i * D + e] = s;
    }
    idxOut[i] = (float)idx;

    // a_d = 200*h_d ; logZ = sum_d log(2cosh(a_d)) = |a| + log1p(exp(-2|a|))
    float a[D];
    float logZ = 0.f;
    #pragma unroll
    for (int d = 0; d < D; d++) {
        a[d] = 200.0f * h[d];
        const float ab = fabsf(a[d]);
        logZ += ab + log1pf(__expf(-2.f * ab));
    }

    // high-7-bit table (dims 0..6), column-major, logZ folded in; coalesced
    #pragma unroll
    for (int m = 0; m < 128; m++) {
        float v = -logZ;
        #pragma unroll
        for (int d = 0; d < 7; d++) v += ((m >> (6 - d)) & 1) ? a[d] : -a[d];
        At[m * NS + i] = v;
    }
    // low-7-bit table (dims 7..13), row-major, float4 stores
    float4* bRow = (float4*)(Bt + (size_t)i * 128);
    #pragma unroll
    for (int l4 = 0; l4 < 32; l4++) {
        float4 v4;
        #pragma unroll
        for (int u = 0; u < 4; u++) {
            const int l = l4 * 4 + u;
            float v = 0.f;
            #pragma unroll
            for (int d = 7; d < D; d++) v += ((l >> (13 - d)) & 1) ? a[d] : -a[d];
            (&v4.x)[u] = v;
        }
        bRow[l4] = v4;
    }

    // block-reduce commit loss -> one partial per block
    __shared__ float red[64];
    red[threadIdx.x] = commit;
    __syncthreads();
    #pragma unroll
    for (int s = 32; s > 0; s >>= 1) {
        if (threadIdx.x < s) red[threadIdx.x] += red[threadIdx.x + s];
        __syncthreads();
    }
    if (threadIdx.x == 0) commitPart[blockIdx.x] = red[0];
}

// ---------------------------------------------------------------------------
// Kernel B: each thread owns 4 consecutive codes; float4 loads of both tables.
//   p_ij = exp(At'[jHi][i] + Bt[i][jLo])   (analytic softmax prob)
//   ent partial: sum p * max(t, ln eps)    (matches -p*log(clip(p,eps)))
//   avg_prob partial: per (part, code) sum_i p
// grid = 16 jblocks * 32 parts = 512 blocks; block covers 1024 codes.
// ---------------------------------------------------------------------------
__global__ __launch_bounds__(256) void lfq_kB(
    const float* __restrict__ At, const float* __restrict__ Bt,
    float* __restrict__ avgPart, float* __restrict__ entPart)
{
    const int b = blockIdx.x;          // 0..511
    const int part = b & (PARTS - 1);  // 0..31
    const int jb = b >> 5;             // 0..15
    const int t = threadIdx.x;
    const int jHi = jb * 8 + (t >> 5);     // high-7-bit index of this thread's 4 codes
    const int lo4 = t & 31;                // float4 slot within the 128-wide row

    const float* aCol = At + (size_t)jHi * NS + part * NSP;
    const float4* bRow = (const float4*)(Bt + (size_t)(part * NSP) * 128);

    float ap0 = 0.f, ap1 = 0.f, ap2 = 0.f, ap3 = 0.f, ent = 0.f;
    for (int i0 = 0; i0 < NSP; i0 += 4) {
        const float4 av4 = *(const float4*)(aCol + i0);
        const float avArr[4] = {av4.x, av4.y, av4.z, av4.w};
        #pragma unroll
        for (int k = 0; k < 4; k++) {
            const float av = avArr[k];
            const float4 bv = bRow[(size_t)(i0 + k) * 32 + lo4];
            const float t0 = av + bv.x;
            const float t1 = av + bv.y;
            const float t2 = av + bv.z;
            const float t3 = av + bv.w;
            const float p0 = __expf(t0);
            const float p1 = __expf(t1);
            const float p2 = __expf(t2);
            const float p3 = __expf(t3);
            ent = fmaf(p0, fmaxf(t0, LNEPS), ent);
            ent = fmaf(p1, fmaxf(t1, LNEPS), ent);
            ent = fmaf(p2, fmaxf(t2, LNEPS), ent);
            ent = fmaf(p3, fmaxf(t3, LNEPS), ent);
            ap0 += p0; ap1 += p1; ap2 += p2; ap3 += p3;
        }
    }

    // coalesced float4 store of the 4 per-code sums
    float4* apOut = (float4*)(avgPart + (size_t)part * CS);
    apOut[jb * 256 + t] = make_float4(ap0, ap1, ap2, ap3);

    __shared__ float red[256];
    red[t] = ent;
    __syncthreads();
    #pragma unroll
    for (int s = 128; s > 0; s >>= 1) {
        if (t < s) red[t] += red[t + s];
        __syncthreads();
    }
    if (t == 0) entPart[b] = red[0];
}

// ---------------------------------------------------------------------------
// Kernel C1: parallel reduction over parts for codebook entropy + entPart.
// grid = 64 blocks * 256 threads; one code per thread.
// ---------------------------------------------------------------------------
__global__ __launch_bounds__(256) void lfq_kC1(
    const float* __restrict__ avgPart, const float* __restrict__ entPart,
    float* __restrict__ cbPart, float* __restrict__ entSub)
{
    const int b = blockIdx.x;
    const int t = threadIdx.x;
    const int j = b * 256 + t;

    float s = 0.f;
    #pragma unroll
    for (int p = 0; p < PARTS; p++) s += avgPart[(size_t)p * CS + j];
    const float q = s * (1.0f / NS);
    float cb = q * __logf(fmaxf(q, EPS));

    float es = (t < 8) ? entPart[b * 8 + t] : 0.f;   // 512 entries / 64 blocks

    __shared__ float r1[256], r2[256];
    r1[t] = cb; r2[t] = es;
    __syncthreads();
    #pragma unroll
    for (int st = 128; st > 0; st >>= 1) {
        if (t < st) { r1[t] += r1[t + st]; r2[t] += r2[t + st]; }
        __syncthreads();
    }
    if (t == 0) { cbPart[b] = r1[0]; entSub[b] = r2[0]; }
}

// ---------------------------------------------------------------------------
// Kernel C2: tiny final combine.
// ---------------------------------------------------------------------------
__global__ __launch_bounds__(256) void lfq_kC2(
    const float* __restrict__ cbPart, const float* __restrict__ entSub,
    const float* __restrict__ commitPart, float* __restrict__ aux)
{
    const int t = threadIdx.x;
    float cb = (t < 64) ? cbPart[t] : 0.f;
    float es = (t < 64) ? entSub[t] : 0.f;
    float cm = (t < 128) ? commitPart[t] : 0.f;

    __shared__ float r1[256], r2[256], r3[256];
    r1[t] = cb; r2[t] = es; r3[t] = cm;
    __syncthreads();
    #pragma unroll
    for (int s = 128; s > 0; s >>= 1) {
        if (t < s) { r1[t] += r1[t + s]; r2[t] += r2[t + s]; r3[t] += r3[t + s]; }
        __syncthreads();
    }
    if (t == 0) {
        const float codebook_entropy = -r1[0];
        const float per_sample_entropy = -r2[0] / (float)NS;
        const float commit_loss = r3[0] / (float)(NS * D);
        const float entropy_aux = per_sample_entropy - 1.0f * codebook_entropy;
        aux[0] = entropy_aux * 0.1f + commit_loss * 0.25f;
    }
}

extern "C" void kernel_launch(void* const* d_in, const int* in_sizes, int n_in,
                              void* d_out, int out_size, void* d_ws, size_t ws_size,
                              hipStream_t stream) {
    const float* x    = (const float*)d_in[0];
    const float* Win  = (const float*)d_in[1];
    const float* bin  = (const float*)d_in[2];
    const float* Wout = (const float*)d_in[3];
    const float* bout = (const float*)d_in[4];

    float* out    = (float*)d_out;            // [NS][D]
    float* idxOut = out + (size_t)NS * D;     // [NS] indices as float
    float* aux    = idxOut + NS;              // scalar

    float* ws         = (float*)d_ws;
    float* At         = ws;                          // 128*NS floats (4MB)
    float* Bt         = At + (size_t)128 * NS;       // NS*128 floats (4MB)
    float* avgPart    = Bt + (size_t)128 * NS;       // PARTS*CS floats (2MB)
    float* entPart    = avgPart + (size_t)PARTS * CS; // 512 floats
    float* commitPart = entPart + 512;               // 128 floats
    float* cbPart     = commitPart + 128;            // 64 floats
    float* entSub     = cbPart + 64;                 // 64 floats

    lfq_kA<<<NS / 64, 64, 0, stream>>>(x, Win, bin, Wout, bout,
                                       out, idxOut, At, Bt, commitPart);
    lfq_kB<<<16 * PARTS, 256, 0, stream>>>(At, Bt, avgPart, entPart);
    lfq_kC1<<<64, 256, 0, stream>>>(avgPart, entPart, cbPart, entSub);
    lfq_kC2<<<1, 256, 0, stream>>>(cbPart, entSub, commitPart, aux);
}

// Round 3
// 27.777 us; speedup vs baseline: 4.4085x; 2.0842x over previous
//
#include <hip/hip_runtime.h>
#include <hip/hip_bf16.h>

#define NS 8192          // 4*2048 samples
#define D 14
#define CS 16384         // 2^14 codes
#define EPS 1e-5f
#define LNEPS (-11.512925464970229f) // ln(1e-5)
#define THRESH 30.0f     // drop codes with logit-gap > 30 (p < 9e-14)

// ---------------------------------------------------------------------------
// Zero the 16384-bin probability histogram (64 KB).
// ---------------------------------------------------------------------------
__global__ __launch_bounds__(256) void lfq_zero(float* __restrict__ hist)
{
    ((float4*)hist)[blockIdx.x * 256 + threadIdx.x] =
        make_float4(0.f, 0.f, 0.f, 0.f);
}

// ---------------------------------------------------------------------------
// Fused main kernel: one thread per sample.
//  - h = x @ Win^T + bin ; q = sign(h) ; out = q @ Wout^T + bout ; idx bits
//  - commit partials (block reduce)
//  - analytic softmax over the sign hypercube:
//      logZ = sum_d log(2 cosh(a_d)),  a_d = 200 h_d
//      t(code) = t0 - sum_{flipped d} 2|a_d|,  t0 = -sum_d log1p(exp(-2|a_d|))
//    Only dims with 2|a_d| < THRESH can produce p above 9e-14; enumerate the
//    2^S sign combos of those "soft" dims via Gray code. All other 16384-2^S
//    codes contribute < 2e-8 total to either entropy term (threshold ~1.5e-2).
//  - per-sample entropy partials: sum p*max(t, ln eps)  (== -p*log(clip(p,eps)))
//  - avg_prob histogram via atomicAdd (sparse, ~4 adds/sample)
// Soft-dim lists live in LDS laid out [k][tid] so the dynamic index k hits
// bank tid%32 -> conflict-free (rule #20: keep runtime-indexed arrays out of
// VGPR arrays, which would spill to scratch).
// ---------------------------------------------------------------------------
__global__ __launch_bounds__(64) void lfq_main(
    const float* __restrict__ x, const float* __restrict__ Win,
    const float* __restrict__ bin, const float* __restrict__ Wout,
    const float* __restrict__ bout,
    float* __restrict__ out, float* __restrict__ idxOut,
    float* __restrict__ hist, float* __restrict__ entPart,
    float* __restrict__ commitPart)
{
    const int tid = threadIdx.x;
    const int i = blockIdx.x * 64 + tid;

    float xv[D];
    #pragma unroll
    for (int k = 0; k < D; k++) xv[k] = x[i * D + k];

    float h[D];
    #pragma unroll
    for (int d = 0; d < D; d++) {
        float s = bin[d];
        #pragma unroll
        for (int k = 0; k < D; k++) s = fmaf(xv[k], Win[d * D + k], s);
        h[d] = s;
    }

    // sign quantization + indices (MSB-first) + commit loss
    float q[D];
    int idx = 0;
    float commit = 0.f;
    #pragma unroll
    for (int d = 0; d < D; d++) {
        const bool pos = h[d] > 0.f;
        q[d] = pos ? 1.f : -1.f;
        idx |= (pos ? 1 : 0) << (13 - d);
        const float e = h[d] - q[d];
        commit = fmaf(e, e, commit);
    }

    // out = q @ Wout^T + bout (forward value of straight-through h_st == q)
    #pragma unroll
    for (int e = 0; e < D; e++) {
        float s = bout[e];
        #pragma unroll
        for (int d = 0; d < D; d++) s = fmaf(q[d], Wout[e * D + d], s);
        out[i * D + e] = s;
    }
    idxOut[i] = (float)idx;

    // soft-dim compaction + t0 = sum|a| - logZ = -sum log1p(exp(-2|a|))
    __shared__ float sA[D * 64];   // 2|a_d| of soft dims, [k][tid]
    __shared__ int   sB[D * 64];   // xor bitmask of soft dims, [k][tid]
    int S = 0;
    float t0 = 0.f;
    #pragma unroll
    for (int d = 0; d < D; d++) {
        const float ab = fabsf(200.0f * h[d]);
        t0 -= __logf(1.0f + __expf(-2.f * ab));
        const float twoA = 2.f * ab;
        if (twoA < THRESH) {
            sA[S * 64 + tid] = twoA;
            sB[S * 64 + tid] = 1 << (13 - d);
            S++;
        }
    }

    // Gray-code enumeration of the 2^S near-max codes
    float ent;
    {
        const float p0 = __expf(t0);
        ent = p0 * fmaxf(t0, LNEPS);
        atomicAdd(&hist[idx], p0);
    }
    float tcur = t0;
    int jj = idx;
    const int total = 1 << S;
    for (int m = 1; m < total; m++) {
        const int k = __ffs(m) - 1;          // bit that toggles this step
        const int gn = m ^ (m >> 1);         // Gray code after the toggle
        const float tw = sA[k * 64 + tid];
        const int bm = sB[k * 64 + tid];
        tcur += ((gn >> k) & 1) ? -tw : tw;  // turned on -> flip costs -2|a|
        jj ^= bm;
        const float p = __expf(tcur);
        ent = fmaf(p, fmaxf(tcur, LNEPS), ent);
        atomicAdd(&hist[jj], p);
    }

    // block reductions for commit + per-sample-entropy partials
    __shared__ float red[64];
    red[tid] = commit;
    __syncthreads();
    #pragma unroll
    for (int s = 32; s > 0; s >>= 1) {
        if (tid < s) red[tid] += red[tid + s];
        __syncthreads();
    }
    if (tid == 0) commitPart[blockIdx.x] = red[0];
    __syncthreads();
    red[tid] = ent;
    __syncthreads();
    #pragma unroll
    for (int s = 32; s > 0; s >>= 1) {
        if (tid < s) red[tid] += red[tid + s];
        __syncthreads();
    }
    if (tid == 0) entPart[blockIdx.x] = red[0];
}

// ---------------------------------------------------------------------------
// R1: codebook-entropy partials from the histogram. 16 blocks x 256 thr x 4.
// ---------------------------------------------------------------------------
__global__ __launch_bounds__(256) void lfq_r1(
    const float* __restrict__ hist, float* __restrict__ cbPart)
{
    const int t = threadIdx.x;
    const float4 v = ((const float4*)hist)[blockIdx.x * 256 + t];
    float cb = 0.f;
    #pragma unroll
    for (int u = 0; u < 4; u++) {
        const float qv = (&v.x)[u] * (1.0f / NS);
        cb += qv * __logf(fmaxf(qv, EPS));
    }
    __shared__ float r[256];
    r[t] = cb;
    __syncthreads();
    #pragma unroll
    for (int s = 128; s > 0; s >>= 1) {
        if (t < s) r[t] += r[t + s];
        __syncthreads();
    }
    if (t == 0) cbPart[blockIdx.x] = r[0];
}

// ---------------------------------------------------------------------------
// R2: final combine into the aux-loss scalar.
// ---------------------------------------------------------------------------
__global__ __launch_bounds__(256) void lfq_r2(
    const float* __restrict__ cbPart, const float* __restrict__ entPart,
    const float* __restrict__ commitPart, float* __restrict__ aux)
{
    const int t = threadIdx.x;
    float cb = (t < 16) ? cbPart[t] : 0.f;
    float es = (t < 128) ? entPart[t] : 0.f;
    float cm = (t < 128) ? commitPart[t] : 0.f;

    __shared__ float r1[256], r2[256], r3[256];
    r1[t] = cb; r2[t] = es; r3[t] = cm;
    __syncthreads();
    #pragma unroll
    for (int s = 128; s > 0; s >>= 1) {
        if (t < s) { r1[t] += r1[t + s]; r2[t] += r2[t + s]; r3[t] += r3[t + s]; }
        __syncthreads();
    }
    if (t == 0) {
        const float codebook_entropy = -r1[0];
        const float per_sample_entropy = -r2[0] / (float)NS;
        const float commit_loss = r3[0] / (float)(NS * D);
        const float entropy_aux = per_sample_entropy - 1.0f * codebook_entropy;
        aux[0] = entropy_aux * 0.1f + commit_loss * 0.25f;
    }
}

extern "C" void kernel_launch(void* const* d_in, const int* in_sizes, int n_in,
                              void* d_out, int out_size, void* d_ws, size_t ws_size,
                              hipStream_t stream) {
    const float* x    = (const float*)d_in[0];
    const float* Win  = (const float*)d_in[1];
    const float* bin  = (const float*)d_in[2];
    const float* Wout = (const float*)d_in[3];
    const float* bout = (const float*)d_in[4];

    float* out    = (float*)d_out;            // [NS][D]
    float* idxOut = out + (size_t)NS * D;     // [NS] indices as float
    float* aux    = idxOut + NS;              // scalar

    float* ws         = (float*)d_ws;
    float* hist       = ws;                   // CS floats (64 KB)
    float* entPart    = hist + CS;            // 128 floats
    float* commitPart = entPart + 128;        // 128 floats
    float* cbPart     = commitPart + 128;     // 16 floats

    lfq_zero<<<16, 256, 0, stream>>>(hist);
    lfq_main<<<NS / 64, 64, 0, stream>>>(x, Win, bin, Wout, bout,
                                         out, idxOut, hist, entPart, commitPart);
    lfq_r1<<<16, 256, 0, stream>>>(hist, cbPart);
    lfq_r2<<<1, 256, 0, stream>>>(cbPart, entPart, commitPart, aux);
}